// Round 4
// baseline (806.131 us; speedup 1.0000x reference)
//
#include <hip/hip_runtime.h>

// Problem: B=512, T=128, I=128, H=512 (fp32 in/out; bf16 MFMA internally)
#define HD 512
#define KD 640
#define G4 2048

typedef short short8 __attribute__((ext_vector_type(8)));
typedef __bf16 bf16x8 __attribute__((ext_vector_type(8)));
typedef float floatx4 __attribute__((ext_vector_type(4)));
typedef unsigned int uintx4 __attribute__((ext_vector_type(4)));

static __device__ __forceinline__ unsigned short f2bf(float f) {
  unsigned int u = __float_as_uint(f);
  u += 0x7fffu + ((u >> 16) & 1u);   // RNE
  return (unsigned short)(u >> 16);
}
static __device__ __forceinline__ float rcp_(float x) {
  return __builtin_amdgcn_rcpf(x);
}
static __device__ __forceinline__ float sigmoidf_(float x) {
  return rcp_(1.f + __expf(-x));
}
static __device__ __forceinline__ float tanhf_(float x) {
  float ax = fabsf(x);
  float e = __expf(-2.f * ax);
  float r = fmaf(-2.f * e, rcp_(1.f + e), 1.f);
  return copysignf(r, x);
}
// agent-coherent 16B store: sc0 sc1 = write-through to MALL
static __device__ __forceinline__ void store16_cc(unsigned long long a, uintx4 v) {
  asm volatile("global_store_dwordx4 %0, %1, off sc0 sc1" :: "v"(a), "v"(v) : "memory");
}
static __device__ __forceinline__ void waitcnt_vm0() {
  asm volatile("s_waitcnt vmcnt(0)" ::: "memory");
}
// global -> LDS direct DMA, 16B/lane, SC0|SC1 (=17) cache policy: bypass L1/L2,
// read at MALL (coherent with store16_cc). LDS dest = wave-uniform base + lane*16.
static __device__ __forceinline__ void load_lds16_cc(const void* g, void* l) {
  __builtin_amdgcn_global_load_lds(
      (const __attribute__((address_space(1))) void*)(unsigned long long)(uintptr_t)g,
      (__attribute__((address_space(3))) void*)l, 16, 0, 17);
}

// ---------------- transpose + cast: src[R][C] fp32 -> dst[C][R] bf16
__global__ __launch_bounds__(256) void transpose_f32_bf16(
    const float* __restrict__ src, unsigned short* __restrict__ dst,
    int R, int C) {
  __shared__ unsigned short tile[64][80];
  int nR = R >> 6;
  int tr = blockIdx.x % nR;
  int tc = blockIdx.x / nR;
  int tid = threadIdx.x;
#pragma unroll
  for (int i = 0; i < 2; ++i) {
    int seg = tid + i * 256;
    int row = seg >> 3, ks8 = (seg & 7) * 8;
    const float* p = src + (size_t)(tr * 64 + row) * C + tc * 64 + ks8;
    short8 v;
#pragma unroll
    for (int q = 0; q < 8; ++q) v[q] = (short)f2bf(p[q]);
    *(short8*)(&tile[row][ks8]) = v;
  }
  __syncthreads();
#pragma unroll
  for (int i = 0; i < 2; ++i) {
    int seg = tid + i * 256;
    int cl = seg >> 3, rs8 = (seg & 7) * 8;
    short8 v;
#pragma unroll
    for (int q = 0; q < 8; ++q) v[q] = (short)tile[rs8 + q][cl];
    *(short8*)(dst + (size_t)(tc * 64 + cl) * R + tr * 64 + rs8) = v;
  }
}

// ---------------- x convert: x[b][t][i] fp32 -> xT[t][b][i] bf16
__global__ __launch_bounds__(256) void xconv(
    const float* __restrict__ xs, const float* __restrict__ xl,
    unsigned short* __restrict__ xTs, unsigned short* __restrict__ xTl) {
  int t = blockIdx.x & 127;
  int bc = (blockIdx.x >> 7) & 3;
  int which = blockIdx.x >> 9;
  const float* x = which ? xl : xs;
  unsigned short* xT = which ? xTl : xTs;
  int b0 = bc * 128;
#pragma unroll
  for (int i = 0; i < 8; ++i) {
    int seg = threadIdx.x + i * 256;
    int bl_ = seg >> 4, i8 = (seg & 15) * 8;
    const float* p = x + (size_t)(b0 + bl_) * 16384 + t * 128 + i8;
    short8 v;
#pragma unroll
    for (int q = 0; q < 8; ++q) v[q] = (short)f2bf(p[q]);
    *(short8*)(xT + ((size_t)t * 512 + b0 + bl_) * 128 + i8) = v;
  }
}

// ---------------- persistent dual-LSTM over all 128 steps (pipelined)
// grid 256 = lstm(2) x mb(16: 32 rows) x nb(8: 64 h)
// wave wn owns h-cols [wn*16,+16) x ALL 4 gates — gate math lane-local.
// Flags: 128B (32 ints) per group -> cacheline-exclusive per exchange group.
// Per step: all-waves poll -> issue h DMA (pre-barrier) -> bar(B) -> x-MFMA
// -> vmcnt(4)+bar(F1): rows 0..15 landed -> x(t+1) prefetch issue +
// mt0 h-MFMA -> vmcnt(2)+bar(F2): all rows landed -> mt1 h-MFMA -> gates
// -> bar(I) -> land x -> h store -> ack -> bar(N) -> flag post.
__global__ __launch_bounds__(256, 1) void lstm_persistent(
    const unsigned short* __restrict__ xTs, const unsigned short* __restrict__ xTl,
    const unsigned short* __restrict__ WTs, const unsigned short* __restrict__ WTl,
    const float* __restrict__ bs, const float* __restrict__ bl,
    unsigned short* __restrict__ hs0, unsigned short* __restrict__ hs1,
    unsigned short* __restrict__ hl0, unsigned short* __restrict__ hl1,
    int* __restrict__ flags) {
  const int bid = blockIdx.x;
  const int lstm = bid & 1;
  const int mb = (bid >> 1) & 15;
  const int nb = bid >> 5;
  const int grp = lstm * 16 + mb;          // 32 groups x 8 blocks
  const int b0 = mb * 32;
  const int H0 = nb * 64;

  const unsigned short* xT = lstm ? xTl : xTs;
  const unsigned short* WT = lstm ? WTl : WTs;
  const float* bias = lstm ? bl : bs;
  unsigned short* h0 = lstm ? hl0 : hs0;
  unsigned short* h1 = lstm ? hl1 : hs1;

  __shared__ unsigned short As[32][648];   // 41472 B; row stride 1296 B
  __shared__ unsigned short hbuf[32][72];  // 4608 B

  const int tid = threadIdx.x;
  const int wn = tid >> 6;
  const int lane = tid & 63;
  const int quad = lane >> 4;
  const int lrow = lane & 15;
  const int colL = wn * 16 + lrow;

  // Non-blocking canary: publish XCC_ID (nothing reads it).
  if (tid == 0) {
    unsigned xcc;
    asm("s_getreg_b32 %0, hwreg(20, 0, 32)" : "=s"(xcc));
    __hip_atomic_store(flags + 1024 + bid, (int)(xcc & 255u) + 1,
                       __ATOMIC_RELAXED, __HIP_MEMORY_SCOPE_AGENT);
  }

  float bias_r[4];
#pragma unroll
  for (int g = 0; g < 4; ++g) bias_r[g] = bias[g * HD + H0 + colL];
  float c_r[8];
#pragma unroll
  for (int j = 0; j < 8; ++j) c_r[j] = 0.f;

  bf16x8 breg[4][20];
#pragma unroll
  for (int g = 0; g < 4; ++g) {
    const unsigned short* wp = WT + (size_t)(g * HD + H0 + colL) * KD + quad * 8;
#pragma unroll
    for (int kc = 0; kc < 20; ++kc)
      breg[g][kc] = __builtin_bit_cast(bf16x8, *(const short8*)(wp + kc * 32));
  }

  const int st_row = tid >> 3, st_c8 = (tid & 7) * 8;
  const unsigned long long hstA =
      (unsigned long long)(h1 + (size_t)(b0 + st_row) * HD + H0 + st_c8);  // t even
  const unsigned long long hstB =
      (unsigned long long)(h0 + (size_t)(b0 + st_row) * HD + H0 + st_c8);  // t odd

  // ---- prologue: stage x(0); zero h-part of As
#pragma unroll
  for (int i = 0; i < 2; ++i) {
    int seg = tid + i * 256;
    int row = seg >> 4, ch = seg & 15;
    short8 v = *(const short8*)(xT + ((size_t)(b0 + row)) * 128 + ch * 8);  // t=0
    *(short8*)(&As[row][ch * 8]) = v;
  }
#pragma unroll
  for (int i = 0; i < 8; ++i) {
    int chunk = tid + i * 256;
    int row = chunk >> 6, ch = chunk & 63;
    *(uintx4*)(&As[row][128 + ch * 8]) = (uintx4){0, 0, 0, 0};
  }

#pragma unroll 1
  for (int t = 0; t < 128; ++t) {
    const unsigned short* hr = (t & 1) ? h1 : h0;

    // (A) poll flags for h(t) — EVERY wave independently (no wave0 funnel)
    if (t > 0) {
      while (true) {
        int v = __hip_atomic_load(flags + grp * 32 + (lane & 7),
                                  __ATOMIC_RELAXED, __HIP_MEMORY_SCOPE_AGENT);
        if (__ballot(v >= t) == 0xFFFFFFFFFFFFFFFFull) break;
        __builtin_amdgcn_s_sleep(1);
      }
      // (C) issue h(t) -> LDS DMA immediately, pre-barrier. Safe: barrier (N)
      // of t-1 guarantees every wave finished its As-h MFMA reads of t-1.
      // Rows 0..15 issued first (i=0..3) to enable the split waits below.
#pragma unroll
      for (int i = 0; i < 8; ++i) {
        int row = wn + i * 4;  // i=0..3 -> rows 0..15; i=4..7 -> rows 16..31
        load_lds16_cc(hr + (size_t)(b0 + row) * HD + lane * 8, &As[row][128]);
      }
    }
    __syncthreads();   // (B) x(t) staged (K2 of t-1) visible to all waves

    // (D) x-part MFMA (kc 0..3), both row-halves, while h loads fly
    floatx4 acc[2][4];
#pragma unroll
    for (int mt = 0; mt < 2; ++mt)
#pragma unroll
      for (int g = 0; g < 4; ++g) acc[mt][g] = (floatx4){0.f, 0.f, 0.f, 0.f};
#pragma unroll
    for (int kc = 0; kc < 4; ++kc) {
      bf16x8 a0 = __builtin_bit_cast(bf16x8, *(const short8*)(&As[lrow][kc * 32 + quad * 8]));
      bf16x8 a1 = __builtin_bit_cast(bf16x8, *(const short8*)(&As[16 + lrow][kc * 32 + quad * 8]));
#pragma unroll
      for (int g = 0; g < 4; ++g) {
        acc[0][g] = __builtin_amdgcn_mfma_f32_16x16x32_bf16(a0, breg[g][kc], acc[0][g], 0, 0, 0);
        acc[1][g] = __builtin_amdgcn_mfma_f32_16x16x32_bf16(a1, breg[g][kc], acc[1][g], 0, 0, 0);
      }
    }

    // (E1) my first 4 DMAs (rows 0..15 slice) landed; (F1) all waves' did
    asm volatile("s_waitcnt vmcnt(4)" ::: "memory");
    __syncthreads();

    // (K1) x(t+1) prefetch issue — unconditional. At t=127 this reads the
    // adjacent allocated workspace buffer (never consumed); keeps the vmcnt
    // arithmetic below step-invariant.
    short8 xv[2];
#pragma unroll
    for (int i = 0; i < 2; ++i) {
      int seg = tid + i * 256;
      int row = seg >> 4, ch = seg & 15;
      xv[i] = *(const short8*)(xT + ((size_t)(t + 1) * 512 + b0 + row) * 128 + ch * 8);
    }

    // (G1) h-part MFMA, rows 0..15 (mt=0), kc 4..19 — overlaps rows 16..31 DMA
#pragma unroll
    for (int kc = 4; kc < 20; ++kc) {
      bf16x8 a0 = __builtin_bit_cast(bf16x8, *(const short8*)(&As[lrow][kc * 32 + quad * 8]));
#pragma unroll
      for (int g = 0; g < 4; ++g)
        acc[0][g] = __builtin_amdgcn_mfma_f32_16x16x32_bf16(a0, breg[g][kc], acc[0][g], 0, 0, 0);
    }

    // (E2) remaining 4 DMAs done (the 2 newest outstanding = K1 x-loads,
    // vmcnt retires in issue order); (F2) all waves' rows landed
    asm volatile("s_waitcnt vmcnt(2)" ::: "memory");
    __syncthreads();

    // (G2) h-part MFMA, rows 16..31 (mt=1), kc 4..19
#pragma unroll
    for (int kc = 4; kc < 20; ++kc) {
      bf16x8 a1 = __builtin_bit_cast(bf16x8, *(const short8*)(&As[16 + lrow][kc * 32 + quad * 8]));
#pragma unroll
      for (int g = 0; g < 4; ++g)
        acc[1][g] = __builtin_amdgcn_mfma_f32_16x16x32_bf16(a1, breg[g][kc], acc[1][g], 0, 0, 0);
    }

    // (H) lane-local gate math -> hbuf
#pragma unroll
    for (int mt = 0; mt < 2; ++mt)
#pragma unroll
      for (int r = 0; r < 4; ++r) {
        int j = mt * 4 + r;
        float fg = acc[mt][0][r] + bias_r[0];
        float ig = acc[mt][1][r] + bias_r[1];
        float og = acc[mt][2][r] + bias_r[2];
        float cg = acc[mt][3][r] + bias_r[3];
        float cn = sigmoidf_(fg) * c_r[j] + sigmoidf_(ig) * tanhf_(cg);
        float hn = sigmoidf_(og) * tanhf_(cn);
        c_r[j] = cn;
        hbuf[mt * 16 + quad * 4 + r][colL] = f2bf(hn);
      }
    __syncthreads();   // (I) hbuf complete; all waves past MFMA reads of As

    // (K2) land x(t+1): outstanding vmem = the 2 x loads (issued ~1500cy ago),
    // so the compiler's auto-wait here is effectively free.
    if (t < 127) {
#pragma unroll
      for (int i = 0; i < 2; ++i) {
        int seg = tid + i * 256;
        int row = seg >> 4, ch = seg & 15;
        *(short8*)(&As[row][ch * 8]) = xv[i];
      }
    }

    // (J) h(t+1) store to MALL
    short8 hv8 = *(const short8*)(&hbuf[st_row][st_c8]);
    store16_cc((t & 1) ? hstB : hstA, __builtin_bit_cast(uintx4, hv8));

    waitcnt_vm0();     // (L) my wave's h store ack'd (drains x loads too)
    __syncthreads();   // (N) ALL waves' stores ack'd — post race fixed
    if (t < 127 && tid == 0)             // (M) publish
      __hip_atomic_store(flags + grp * 32 + nb, t + 1,
                         __ATOMIC_RELAXED, __HIP_MEMORY_SCOPE_AGENT);
  }
}

// ---------------- out = tanh(concat(hs,hl) @ out_W + out_b), fp32 out
__global__ __launch_bounds__(256) void out_gemm(
    const unsigned short* __restrict__ hs, const unsigned short* __restrict__ hl,
    const unsigned short* __restrict__ WTo,  // [512][1024] bf16
    const float* __restrict__ ob, float* __restrict__ out) {
  const int bx = blockIdx.x;
  const int mb = bx & 7;
  const int nb = bx >> 3;

  __shared__ unsigned short As2[64][88];
  __shared__ unsigned short Bs2[128][88];

  const int tid = threadIdx.x;
  const int wave = tid >> 6;
  const int lane = tid & 63;
  const int quad = lane >> 4;
  const int lrow = lane & 15;
  const int wm = wave & 1;
  const int wn = wave >> 1;

  floatx4 acc[8];
#pragma unroll
  for (int i = 0; i < 8; ++i) acc[i] = (floatx4){0.f, 0.f, 0.f, 0.f};

  for (int k0 = 0; k0 < 1024; k0 += 64) {
#pragma unroll
    for (int i = 0; i < 2; ++i) {
      int seg = tid + i * 256;
      int row = seg >> 3, ks8 = (seg & 7) * 8;
      int kg = k0 + ks8;
      int b = mb * 64 + row;
      const unsigned short* src =
          (kg < 512) ? (hs + (size_t)b * HD + kg) : (hl + (size_t)b * HD + (kg - 512));
      *(short8*)(&As2[row][ks8]) = *(const short8*)src;
    }
#pragma unroll
    for (int i = 0; i < 4; ++i) {
      int seg = tid + i * 256;
      int n = seg >> 3, ks8 = (seg & 7) * 8;
      *(short8*)(&Bs2[n][ks8]) =
          *(const short8*)(WTo + (size_t)(nb * 128 + n) * 1024 + k0 + ks8);
    }
    __syncthreads();
#pragma unroll
    for (int ks = 0; ks < 64; ks += 32) {
      int kq = ks + quad * 8;
      bf16x8 a0 = __builtin_bit_cast(bf16x8, *(const short8*)(&As2[wm * 32 + lrow][kq]));
      bf16x8 a1 = __builtin_bit_cast(bf16x8, *(const short8*)(&As2[wm * 32 + 16 + lrow][kq]));
#pragma unroll
      for (int nt = 0; nt < 4; ++nt) {
        bf16x8 bfr = __builtin_bit_cast(bf16x8, *(const short8*)(&Bs2[wn * 64 + nt * 16 + lrow][kq]));
        acc[nt] = __builtin_amdgcn_mfma_f32_16x16x32_bf16(a0, bfr, acc[nt], 0, 0, 0);
        acc[4 + nt] = __builtin_amdgcn_mfma_f32_16x16x32_bf16(a1, bfr, acc[4 + nt], 0, 0, 0);
      }
    }
    __syncthreads();
  }
#pragma unroll
  for (int mt = 0; mt < 2; ++mt) {
#pragma unroll
    for (int nt = 0; nt < 4; ++nt) {
      int n = nb * 128 + wn * 64 + nt * 16 + lrow;
      float bv = ob[n];
#pragma unroll
      for (int r = 0; r < 4; ++r) {
        int b = mb * 64 + wm * 32 + mt * 16 + quad * 4 + r;
        out[(size_t)b * HD + n] = tanhf_(acc[mt * 4 + nt][r] + bv);
      }
    }
  }
}

extern "C" void kernel_launch(void* const* d_in, const int* in_sizes, int n_in,
                              void* d_out, int out_size, void* d_ws, size_t ws_size,
                              hipStream_t stream) {
  (void)in_sizes; (void)n_in; (void)out_size; (void)ws_size;
  const float* xs = (const float*)d_in[0];
  const float* xl = (const float*)d_in[1];
  const float* sW = (const float*)d_in[4];
  const float* sb = (const float*)d_in[5];
  const float* lW = (const float*)d_in[6];
  const float* lb = (const float*)d_in[7];
  const float* oW = (const float*)d_in[8];
  const float* ob = (const float*)d_in[9];

  char* w = (char*)d_ws;
  int* flags = (int*)w;                                 // 32 grp x 32 ints (128B/grp) + canary
  unsigned short* WTs = (unsigned short*)(w + 8192);    // [2048][640]
  unsigned short* WTl = WTs + (size_t)G4 * KD;
  unsigned short* WTo = WTl + (size_t)G4 * KD;          // [512][1024]
  unsigned short* xTs = WTo + (size_t)HD * 1024;        // [128][512][128]
  unsigned short* xTl = xTs + (size_t)128 * 512 * 128;
  unsigned short* hs0 = xTl + (size_t)128 * 512 * 128;
  unsigned short* hs1 = hs0 + (size_t)512 * HD;
  unsigned short* hl0 = hs1 + (size_t)512 * HD;
  unsigned short* hl1 = hl0 + (size_t)512 * HD;

  hipMemsetAsync(flags, 0, 8192, stream);
  transpose_f32_bf16<<<(640 / 64) * (2048 / 64), 256, 0, stream>>>(sW, WTs, 640, 2048);
  transpose_f32_bf16<<<(640 / 64) * (2048 / 64), 256, 0, stream>>>(lW, WTl, 640, 2048);
  transpose_f32_bf16<<<(1024 / 64) * (512 / 64), 256, 0, stream>>>(oW, WTo, 1024, 512);
  xconv<<<1024, 256, 0, stream>>>(xs, xl, xTs, xTl);

  const float* sbp = sb; const float* lbp = lb;
  const unsigned short *xTs_c = xTs, *xTl_c = xTl, *WTs_c = WTs, *WTl_c = WTl;
  unsigned short *a_hs0 = hs0, *a_hs1 = hs1, *a_hl0 = hl0, *a_hl1 = hl1;
  int* a_flags = flags;
  void* args[] = {(void*)&xTs_c, (void*)&xTl_c, (void*)&WTs_c, (void*)&WTl_c,
                  (void*)&sbp, (void*)&lbp, (void*)&a_hs0, (void*)&a_hs1,
                  (void*)&a_hl0, (void*)&a_hl1, (void*)&a_flags};
  hipError_t e = hipLaunchCooperativeKernel((const void*)lstm_persistent,
                                            dim3(256), dim3(256), args, 0, stream);
  if (e != hipSuccess) {
    lstm_persistent<<<256, 256, 0, stream>>>(xTs, xTl, WTs, WTl, sb, lb,
                                             hs0, hs1, hl0, hl1, flags);
  }
  // t=127 (odd) wrote h0 buffers
  out_gemm<<<32, 256, 0, stream>>>(hs0, hl0, WTo, ob, (float*)d_out);
}

// Round 5
// 716.873 us; speedup vs baseline: 1.1245x; 1.1245x over previous
//
#include <hip/hip_runtime.h>

// Problem: B=512, T=128, I=128, H=512 (fp32 in/out; bf16 MFMA internally)
#define HD 512
#define KD 640
#define G4 2048

typedef short short8 __attribute__((ext_vector_type(8)));
typedef __bf16 bf16x8 __attribute__((ext_vector_type(8)));
typedef float floatx4 __attribute__((ext_vector_type(4)));
typedef unsigned int uintx4 __attribute__((ext_vector_type(4)));

static __device__ __forceinline__ unsigned short f2bf(float f) {
  unsigned int u = __float_as_uint(f);
  u += 0x7fffu + ((u >> 16) & 1u);   // RNE
  return (unsigned short)(u >> 16);
}
static __device__ __forceinline__ float rcp_(float x) {
  return __builtin_amdgcn_rcpf(x);
}
static __device__ __forceinline__ float sigmoidf_(float x) {
  return rcp_(1.f + __expf(-x));
}
static __device__ __forceinline__ float tanhf_(float x) {
  float ax = fabsf(x);
  float e = __expf(-2.f * ax);
  float r = fmaf(-2.f * e, rcp_(1.f + e), 1.f);
  return copysignf(r, x);
}
// agent-coherent 16B store: sc0 sc1 = write-through to MALL
static __device__ __forceinline__ void store16_cc(unsigned long long a, uintx4 v) {
  asm volatile("global_store_dwordx4 %0, %1, off sc0 sc1" :: "v"(a), "v"(v) : "memory");
}
static __device__ __forceinline__ void waitcnt_vm0() {
  asm volatile("s_waitcnt vmcnt(0)" ::: "memory");
}
// global -> LDS direct DMA, 16B/lane, SC0|SC1 (=17) cache policy: bypass L1/L2,
// read at MALL (coherent with store16_cc). LDS dest = wave-uniform base + lane*16.
static __device__ __forceinline__ void load_lds16_cc(const void* g, void* l) {
  __builtin_amdgcn_global_load_lds(
      (const __attribute__((address_space(1))) void*)(unsigned long long)(uintptr_t)g,
      (__attribute__((address_space(3))) void*)l, 16, 0, 17);
}

// ---------------- transpose + cast: src[R][C] fp32 -> dst[C][R] bf16
__global__ __launch_bounds__(256) void transpose_f32_bf16(
    const float* __restrict__ src, unsigned short* __restrict__ dst,
    int R, int C) {
  __shared__ unsigned short tile[64][80];
  int nR = R >> 6;
  int tr = blockIdx.x % nR;
  int tc = blockIdx.x / nR;
  int tid = threadIdx.x;
#pragma unroll
  for (int i = 0; i < 2; ++i) {
    int seg = tid + i * 256;
    int row = seg >> 3, ks8 = (seg & 7) * 8;
    const float* p = src + (size_t)(tr * 64 + row) * C + tc * 64 + ks8;
    short8 v;
#pragma unroll
    for (int q = 0; q < 8; ++q) v[q] = (short)f2bf(p[q]);
    *(short8*)(&tile[row][ks8]) = v;
  }
  __syncthreads();
#pragma unroll
  for (int i = 0; i < 2; ++i) {
    int seg = tid + i * 256;
    int cl = seg >> 3, rs8 = (seg & 7) * 8;
    short8 v;
#pragma unroll
    for (int q = 0; q < 8; ++q) v[q] = (short)tile[rs8 + q][cl];
    *(short8*)(dst + (size_t)(tc * 64 + cl) * R + tr * 64 + rs8) = v;
  }
}

// ---------------- x convert: x[b][t][i] fp32 -> xT[t][b][i] bf16
__global__ __launch_bounds__(256) void xconv(
    const float* __restrict__ xs, const float* __restrict__ xl,
    unsigned short* __restrict__ xTs, unsigned short* __restrict__ xTl) {
  int t = blockIdx.x & 127;
  int bc = (blockIdx.x >> 7) & 3;
  int which = blockIdx.x >> 9;
  const float* x = which ? xl : xs;
  unsigned short* xT = which ? xTl : xTs;
  int b0 = bc * 128;
#pragma unroll
  for (int i = 0; i < 8; ++i) {
    int seg = threadIdx.x + i * 256;
    int bl_ = seg >> 4, i8 = (seg & 15) * 8;
    const float* p = x + (size_t)(b0 + bl_) * 16384 + t * 128 + i8;
    short8 v;
#pragma unroll
    for (int q = 0; q < 8; ++q) v[q] = (short)f2bf(p[q]);
    *(short8*)(xT + ((size_t)t * 512 + b0 + bl_) * 128 + i8) = v;
  }
}

// ---------------- persistent dual-LSTM over all 128 steps (pipelined)
// grid 256 = lstm(2) x mb(16: 32 rows) x nb(8: 64 h)
// wave wn owns h-cols [wn*16,+16) x ALL 4 gates — gate math lane-local.
// Flags: 128B (32 ints) per group -> cacheline-exclusive per exchange group.
// TWO barriers per step (R4 lesson: each __syncthreads ~200cy here):
//   poll -> bar(B) -> issue h DMA -> x-MFMA -> vmcnt0 -> bar(F)
//   -> x(t+1) prefetch issue -> h-MFMA -> gates -> WAVE-PRIVATE LDS
//   transpose (lgkmcnt only, no barrier) -> h store -> ack -> flag post
//   -> land x(t+1).
// Barrier (I) removed: h-store transpose is wave-private; As-h overwrite by
// next step's DMA is protected by (B) of t+1 (DMA issue is post-B, and all
// As reads of step t precede each wave's arrival at B of t+1).
__global__ __launch_bounds__(256, 1) void lstm_persistent(
    const unsigned short* __restrict__ xTs, const unsigned short* __restrict__ xTl,
    const unsigned short* __restrict__ WTs, const unsigned short* __restrict__ WTl,
    const float* __restrict__ bs, const float* __restrict__ bl,
    unsigned short* __restrict__ hs0, unsigned short* __restrict__ hs1,
    unsigned short* __restrict__ hl0, unsigned short* __restrict__ hl1,
    int* __restrict__ flags) {
  const int bid = blockIdx.x;
  const int lstm = bid & 1;
  const int mb = (bid >> 1) & 15;
  const int nb = bid >> 5;
  const int grp = lstm * 16 + mb;          // 32 groups x 8 blocks
  const int b0 = mb * 32;
  const int H0 = nb * 64;

  const unsigned short* xT = lstm ? xTl : xTs;
  const unsigned short* WT = lstm ? WTl : WTs;
  const float* bias = lstm ? bl : bs;
  unsigned short* h0 = lstm ? hl0 : hs0;
  unsigned short* h1 = lstm ? hl1 : hs1;

  __shared__ unsigned short As[32][648];    // 41472 B; row stride 1296 B
  __shared__ unsigned short hbw[4][32][24]; // 6144 B; wave-private transpose

  const int tid = threadIdx.x;
  const int wn = tid >> 6;
  const int lane = tid & 63;
  const int quad = lane >> 4;
  const int lrow = lane & 15;
  const int colL = wn * 16 + lrow;

  // Non-blocking canary: publish XCC_ID (nothing reads it).
  if (tid == 0) {
    unsigned xcc;
    asm("s_getreg_b32 %0, hwreg(20, 0, 32)" : "=s"(xcc));
    __hip_atomic_store(flags + 1024 + bid, (int)(xcc & 255u) + 1,
                       __ATOMIC_RELAXED, __HIP_MEMORY_SCOPE_AGENT);
  }

  float bias_r[4];
#pragma unroll
  for (int g = 0; g < 4; ++g) bias_r[g] = bias[g * HD + H0 + colL];
  float c_r[8];
#pragma unroll
  for (int j = 0; j < 8; ++j) c_r[j] = 0.f;

  bf16x8 breg[4][20];
#pragma unroll
  for (int g = 0; g < 4; ++g) {
    const unsigned short* wp = WT + (size_t)(g * HD + H0 + colL) * KD + quad * 8;
#pragma unroll
    for (int kc = 0; kc < 20; ++kc)
      breg[g][kc] = __builtin_bit_cast(bf16x8, *(const short8*)(wp + kc * 32));
  }

  // Store mapping (wave-private slab): wave wn stores rows (lane>>1),
  // cols H0 + wn*16 + (lane&1)*8 .. +8  — 16B per lane, full 32x16 slab.
  const int srow = lane >> 1, sc8 = (lane & 1) * 8;
  const unsigned long long hstA =
      (unsigned long long)(h1 + (size_t)(b0 + srow) * HD + H0 + wn * 16 + sc8);  // t even
  const unsigned long long hstB =
      (unsigned long long)(h0 + (size_t)(b0 + srow) * HD + H0 + wn * 16 + sc8);  // t odd

  // ---- prologue: stage x(0); zero h-part of As
#pragma unroll
  for (int i = 0; i < 2; ++i) {
    int seg = tid + i * 256;
    int row = seg >> 4, ch = seg & 15;
    short8 v = *(const short8*)(xT + ((size_t)(b0 + row)) * 128 + ch * 8);  // t=0
    *(short8*)(&As[row][ch * 8]) = v;
  }
#pragma unroll
  for (int i = 0; i < 8; ++i) {
    int chunk = tid + i * 256;
    int row = chunk >> 6, ch = chunk & 63;
    *(uintx4*)(&As[row][128 + ch * 8]) = (uintx4){0, 0, 0, 0};
  }

#pragma unroll 1
  for (int t = 0; t < 128; ++t) {
    const unsigned short* hr = (t & 1) ? h1 : h0;

    // (A) poll flags for h(t) — wave 0 (others wait at B; same detect time)
    if (t > 0 && wn == 0) {
      while (true) {
        int v = __hip_atomic_load(flags + grp * 32 + (lane & 7),
                                  __ATOMIC_RELAXED, __HIP_MEMORY_SCOPE_AGENT);
        if (__ballot(v >= t) == 0xFFFFFFFFFFFFFFFFull) break;
        __builtin_amdgcn_s_sleep(1);
      }
    }
    __syncthreads();   // (B) x(t) staged visible; flags passed; As reads of t-1 done

    // (C) issue h(t) -> LDS direct DMA (wave-uniform row per iteration)
    if (t > 0) {
#pragma unroll
      for (int i = 0; i < 8; ++i) {
        int row = wn + i * 4;  // (wn*64 + i*256) >> 6
        load_lds16_cc(hr + (size_t)(b0 + row) * HD + lane * 8, &As[row][128]);
      }
    }

    // (D) x-part MFMA (kc 0..3) while h loads are in flight
    floatx4 acc[2][4];
#pragma unroll
    for (int mt = 0; mt < 2; ++mt)
#pragma unroll
      for (int g = 0; g < 4; ++g) acc[mt][g] = (floatx4){0.f, 0.f, 0.f, 0.f};
#pragma unroll
    for (int kc = 0; kc < 4; ++kc) {
      bf16x8 a0 = __builtin_bit_cast(bf16x8, *(const short8*)(&As[lrow][kc * 32 + quad * 8]));
      bf16x8 a1 = __builtin_bit_cast(bf16x8, *(const short8*)(&As[16 + lrow][kc * 32 + quad * 8]));
#pragma unroll
      for (int g = 0; g < 4; ++g) {
        acc[0][g] = __builtin_amdgcn_mfma_f32_16x16x32_bf16(a0, breg[g][kc], acc[0][g], 0, 0, 0);
        acc[1][g] = __builtin_amdgcn_mfma_f32_16x16x32_bf16(a1, breg[g][kc], acc[1][g], 0, 0, 0);
      }
    }

    waitcnt_vm0();     // (E) my 8 h DMAs landed
    __syncthreads();   // (F) all waves' h landed; As-x readers (D) done

    // (K1) x(t+1) prefetch issue — unconditional (t=127 reads the adjacent
    // allocated workspace buffer; never consumed). Latency hides under (G).
    short8 xv[2];
#pragma unroll
    for (int i = 0; i < 2; ++i) {
      int seg = tid + i * 256;
      int row = seg >> 4, ch = seg & 15;
      xv[i] = *(const short8*)(xT + ((size_t)(t + 1) * 512 + b0 + row) * 128 + ch * 8);
    }

    // (G) h-part MFMA (kc 4..19)
#pragma unroll
    for (int kc = 4; kc < 20; ++kc) {
      bf16x8 a0 = __builtin_bit_cast(bf16x8, *(const short8*)(&As[lrow][kc * 32 + quad * 8]));
      bf16x8 a1 = __builtin_bit_cast(bf16x8, *(const short8*)(&As[16 + lrow][kc * 32 + quad * 8]));
#pragma unroll
      for (int g = 0; g < 4; ++g) {
        acc[0][g] = __builtin_amdgcn_mfma_f32_16x16x32_bf16(a0, breg[g][kc], acc[0][g], 0, 0, 0);
        acc[1][g] = __builtin_amdgcn_mfma_f32_16x16x32_bf16(a1, breg[g][kc], acc[1][g], 0, 0, 0);
      }
    }

    // (H) lane-local gate math -> wave-private transpose scratch
#pragma unroll
    for (int mt = 0; mt < 2; ++mt)
#pragma unroll
      for (int r = 0; r < 4; ++r) {
        int j = mt * 4 + r;
        float fg = acc[mt][0][r] + bias_r[0];
        float ig = acc[mt][1][r] + bias_r[1];
        float og = acc[mt][2][r] + bias_r[2];
        float cg = acc[mt][3][r] + bias_r[3];
        float cn = sigmoidf_(fg) * c_r[j] + sigmoidf_(ig) * tanhf_(cg);
        float hn = sigmoidf_(og) * tanhf_(cn);
        c_r[j] = cn;
        hbw[wn][mt * 16 + quad * 4 + r][lrow] = f2bf(hn);
      }
    // same-wave LDS RAW: lgkmcnt only, NO barrier (wave-private buffer)
    asm volatile("s_waitcnt lgkmcnt(0)" ::: "memory");
    short8 hv8 = *(const short8*)(&hbw[wn][srow][sc8]);

    // (J) h(t+1) store to MALL
    store16_cc((t & 1) ? hstB : hstA, __builtin_bit_cast(uintx4, hv8));

    waitcnt_vm0();     // (L) my wave's store ack'd (x loads drained too)
    if (t < 127 && tid == 0)             // (M) publish ASAP
      __hip_atomic_store(flags + grp * 32 + nb, t + 1,
                         __ATOMIC_RELAXED, __HIP_MEMORY_SCOPE_AGENT);

    // (K2) land x(t+1) into As (regs valid; readers gated by (B) of t+1)
    if (t < 127) {
#pragma unroll
      for (int i = 0; i < 2; ++i) {
        int seg = tid + i * 256;
        int row = seg >> 4, ch = seg & 15;
        *(short8*)(&As[row][ch * 8]) = xv[i];
      }
    }
  }
}

// ---------------- out = tanh(concat(hs,hl) @ out_W + out_b), fp32 out
__global__ __launch_bounds__(256) void out_gemm(
    const unsigned short* __restrict__ hs, const unsigned short* __restrict__ hl,
    const unsigned short* __restrict__ WTo,  // [512][1024] bf16
    const float* __restrict__ ob, float* __restrict__ out) {
  const int bx = blockIdx.x;
  const int mb = bx & 7;
  const int nb = bx >> 3;

  __shared__ unsigned short As2[64][88];
  __shared__ unsigned short Bs2[128][88];

  const int tid = threadIdx.x;
  const int wave = tid >> 6;
  const int lane = tid & 63;
  const int quad = lane >> 4;
  const int lrow = lane & 15;
  const int wm = wave & 1;
  const int wn = wave >> 1;

  floatx4 acc[8];
#pragma unroll
  for (int i = 0; i < 8; ++i) acc[i] = (floatx4){0.f, 0.f, 0.f, 0.f};

  for (int k0 = 0; k0 < 1024; k0 += 64) {
#pragma unroll
    for (int i = 0; i < 2; ++i) {
      int seg = tid + i * 256;
      int row = seg >> 3, ks8 = (seg & 7) * 8;
      int kg = k0 + ks8;
      int b = mb * 64 + row;
      const unsigned short* src =
          (kg < 512) ? (hs + (size_t)b * HD + kg) : (hl + (size_t)b * HD + (kg - 512));
      *(short8*)(&As2[row][ks8]) = *(const short8*)src;
    }
#pragma unroll
    for (int i = 0; i < 4; ++i) {
      int seg = tid + i * 256;
      int n = seg >> 3, ks8 = (seg & 7) * 8;
      *(short8*)(&Bs2[n][ks8]) =
          *(const short8*)(WTo + (size_t)(nb * 128 + n) * 1024 + k0 + ks8);
    }
    __syncthreads();
#pragma unroll
    for (int ks = 0; ks < 64; ks += 32) {
      int kq = ks + quad * 8;
      bf16x8 a0 = __builtin_bit_cast(bf16x8, *(const short8*)(&As2[wm * 32 + lrow][kq]));
      bf16x8 a1 = __builtin_bit_cast(bf16x8, *(const short8*)(&As2[wm * 32 + 16 + lrow][kq]));
#pragma unroll
      for (int nt = 0; nt < 4; ++nt) {
        bf16x8 bfr = __builtin_bit_cast(bf16x8, *(const short8*)(&Bs2[wn * 64 + nt * 16 + lrow][kq]));
        acc[nt] = __builtin_amdgcn_mfma_f32_16x16x32_bf16(a0, bfr, acc[nt], 0, 0, 0);
        acc[4 + nt] = __builtin_amdgcn_mfma_f32_16x16x32_bf16(a1, bfr, acc[4 + nt], 0, 0, 0);
      }
    }
    __syncthreads();
  }
#pragma unroll
  for (int mt = 0; mt < 2; ++mt) {
#pragma unroll
    for (int nt = 0; nt < 4; ++nt) {
      int n = nb * 128 + wn * 64 + nt * 16 + lrow;
      float bv = ob[n];
#pragma unroll
      for (int r = 0; r < 4; ++r) {
        int b = mb * 64 + wm * 32 + mt * 16 + quad * 4 + r;
        out[(size_t)b * HD + n] = tanhf_(acc[mt * 4 + nt][r] + bv);
      }
    }
  }
}

extern "C" void kernel_launch(void* const* d_in, const int* in_sizes, int n_in,
                              void* d_out, int out_size, void* d_ws, size_t ws_size,
                              hipStream_t stream) {
  (void)in_sizes; (void)n_in; (void)out_size; (void)ws_size;
  const float* xs = (const float*)d_in[0];
  const float* xl = (const float*)d_in[1];
  const float* sW = (const float*)d_in[4];
  const float* sb = (const float*)d_in[5];
  const float* lW = (const float*)d_in[6];
  const float* lb = (const float*)d_in[7];
  const float* oW = (const float*)d_in[8];
  const float* ob = (const float*)d_in[9];

  char* w = (char*)d_ws;
  int* flags = (int*)w;                                 // 32 grp x 32 ints (128B/grp) + canary
  unsigned short* WTs = (unsigned short*)(w + 8192);    // [2048][640]
  unsigned short* WTl = WTs + (size_t)G4 * KD;
  unsigned short* WTo = WTl + (size_t)G4 * KD;          // [512][1024]
  unsigned short* xTs = WTo + (size_t)HD * 1024;        // [128][512][128]
  unsigned short* xTl = xTs + (size_t)128 * 512 * 128;
  unsigned short* hs0 = xTl + (size_t)128 * 512 * 128;
  unsigned short* hs1 = hs0 + (size_t)512 * HD;
  unsigned short* hl0 = hs1 + (size_t)512 * HD;
  unsigned short* hl1 = hl0 + (size_t)512 * HD;

  hipMemsetAsync(flags, 0, 8192, stream);
  transpose_f32_bf16<<<(640 / 64) * (2048 / 64), 256, 0, stream>>>(sW, WTs, 640, 2048);
  transpose_f32_bf16<<<(640 / 64) * (2048 / 64), 256, 0, stream>>>(lW, WTl, 640, 2048);
  transpose_f32_bf16<<<(1024 / 64) * (512 / 64), 256, 0, stream>>>(oW, WTo, 1024, 512);
  xconv<<<1024, 256, 0, stream>>>(xs, xl, xTs, xTl);

  const float* sbp = sb; const float* lbp = lb;
  const unsigned short *xTs_c = xTs, *xTl_c = xTl, *WTs_c = WTs, *WTl_c = WTl;
  unsigned short *a_hs0 = hs0, *a_hs1 = hs1, *a_hl0 = hl0, *a_hl1 = hl1;
  int* a_flags = flags;
  void* args[] = {(void*)&xTs_c, (void*)&xTl_c, (void*)&WTs_c, (void*)&WTl_c,
                  (void*)&sbp, (void*)&lbp, (void*)&a_hs0, (void*)&a_hs1,
                  (void*)&a_hl0, (void*)&a_hl1, (void*)&a_flags};
  hipError_t e = hipLaunchCooperativeKernel((const void*)lstm_persistent,
                                            dim3(256), dim3(256), args, 0, stream);
  if (e != hipSuccess) {
    lstm_persistent<<<256, 256, 0, stream>>>(xTs, xTl, WTs, WTl, sb, lb,
                                             hs0, hs1, hl0, hl1, flags);
  }
  // t=127 (odd) wrote h0 buffers
  out_gemm<<<32, 256, 0, stream>>>(hs0, hl0, WTo, ob, (float*)d_out);
}